// Round 4
// baseline (233.979 us; speedup 1.0000x reference)
//
#include <hip/hip_runtime.h>

// out = sign * FWHT(x), x: 16384 x 2048 fp32; scale 2^-5.5 fused; sign = -1
// for n >= 1536.
//
// One wave per row-stream, 4 rows/wave, software-pipelined: loads for row
// r+1 issue before compute of row r, so VMEM stays fed while the butterfly
// network runs. Grid 1024 blocks = 4 blocks/CU = 16 waves/CU, one generation.
//
// Butterfly ladder (validated R3): bits 0,1 in-register (e); bits 8,9,10
// in-register (k); bits 2,3 DPP quad_perm; bits 4,5 ds_swizzle; bits 7,6 via
// permlane32/16_swap + register butterfly. Store layout after swaps:
//   n = k2*1024 + k1*512 + l5*256 + l4*128 + k0*64 + (l&15)*4 + e
// sign = -M for k>=6 (n10&n9).

#define NN 2048
#define RPW 4  // rows per wave

typedef float f4 __attribute__((ext_vector_type(4)));
typedef unsigned int v2u __attribute__((ext_vector_type(2)));

template <int CTRL>
__device__ __forceinline__ float dppf(float x) {
    return __int_as_float(__builtin_amdgcn_mov_dpp(__float_as_int(x), CTRL, 0xF, 0xF, true));
}
template <int MASK>
__device__ __forceinline__ float swzf(float x) {
    return __int_as_float(__builtin_amdgcn_ds_swizzle(__float_as_int(x), (MASK << 10) | 0x1F));
}
__device__ __forceinline__ void pl32_swap(float& a, float& b) {
    v2u r = __builtin_amdgcn_permlane32_swap(__float_as_uint(a), __float_as_uint(b), false, false);
    a = __uint_as_float(r[0]);
    b = __uint_as_float(r[1]);
}
__device__ __forceinline__ void pl16_swap(float& a, float& b) {
    v2u r = __builtin_amdgcn_permlane16_swap(__float_as_uint(a), __float_as_uint(b), false, false);
    a = __uint_as_float(r[0]);
    b = __uint_as_float(r[1]);
}

// Full butterfly + scale/sign + store for one row held in q[8].
__device__ __forceinline__ void fwht_row_store(f4 q[8], float* __restrict__ outr, int lane) {
    float v[8][4];
#pragma unroll
    for (int k = 0; k < 8; ++k)
#pragma unroll
        for (int e = 0; e < 4; ++e) v[k][e] = q[k][e];

    // ---- bits 0,1 (e), per k ----
#pragma unroll
    for (int k = 0; k < 8; ++k) {
        float a0 = v[k][0], a1 = v[k][1], a2 = v[k][2], a3 = v[k][3];
        float b0 = a0 + a1, b1 = a0 - a1, b2 = a2 + a3, b3 = a2 - a3;
        v[k][0] = b0 + b2; v[k][1] = b1 + b3;
        v[k][2] = b0 - b2; v[k][3] = b1 - b3;
    }
    // ---- bits 8,9,10 (k) ----
#pragma unroll
    for (int e = 0; e < 4; ++e) {
#pragma unroll
        for (int k = 0; k < 8; k += 2) {
            float a = v[k][e], b = v[k + 1][e];
            v[k][e] = a + b; v[k + 1][e] = a - b;
        }
#pragma unroll
        for (int k = 0; k < 8; k += 4) {
            float a0 = v[k][e], a1 = v[k + 1][e], b0 = v[k + 2][e], b1 = v[k + 3][e];
            v[k][e] = a0 + b0; v[k + 1][e] = a1 + b1;
            v[k + 2][e] = a0 - b0; v[k + 3][e] = a1 - b1;
        }
#pragma unroll
        for (int k = 0; k < 4; ++k) {
            float a = v[k][e], b = v[k + 4][e];
            v[k][e] = a + b; v[k + 4][e] = a - b;
        }
    }
    // ---- bit 2: lane xor 1 (DPP quad_perm 0xB1) ----
    {
        const float s = (lane & 1) ? -1.0f : 1.0f;
#pragma unroll
        for (int k = 0; k < 8; ++k)
#pragma unroll
            for (int e = 0; e < 4; ++e) {
                const float w = dppf<0xB1>(v[k][e]);
                v[k][e] = fmaf(s, v[k][e], w);
            }
    }
    // ---- bit 3: lane xor 2 (DPP quad_perm 0x4E) ----
    {
        const float s = (lane & 2) ? -1.0f : 1.0f;
#pragma unroll
        for (int k = 0; k < 8; ++k)
#pragma unroll
            for (int e = 0; e < 4; ++e) {
                const float w = dppf<0x4E>(v[k][e]);
                v[k][e] = fmaf(s, v[k][e], w);
            }
    }
    // ---- bit 4: lane xor 4 (ds_swizzle) ----
    {
        const float s = (lane & 4) ? -1.0f : 1.0f;
#pragma unroll
        for (int k = 0; k < 8; ++k)
#pragma unroll
            for (int e = 0; e < 4; ++e) {
                const float w = swzf<4>(v[k][e]);
                v[k][e] = fmaf(s, v[k][e], w);
            }
    }
    // ---- bit 5: lane xor 8 (ds_swizzle) ----
    {
        const float s = (lane & 8) ? -1.0f : 1.0f;
#pragma unroll
        for (int k = 0; k < 8; ++k)
#pragma unroll
            for (int e = 0; e < 4; ++e) {
                const float w = swzf<8>(v[k][e]);
                v[k][e] = fmaf(s, v[k][e], w);
            }
    }
    // ---- bit 7: permlane32_swap + reg butterfly ----
#pragma unroll
    for (int j = 0; j < 4; ++j)
#pragma unroll
        for (int e = 0; e < 4; ++e) {
            pl32_swap(v[2 * j][e], v[2 * j + 1][e]);
            float a = v[2 * j][e], b = v[2 * j + 1][e];
            v[2 * j][e] = a + b; v[2 * j + 1][e] = a - b;
        }
    // ---- bit 6: permlane16_swap + reg butterfly ----
#pragma unroll
    for (int j = 0; j < 4; ++j)
#pragma unroll
        for (int e = 0; e < 4; ++e) {
            pl16_swap(v[2 * j][e], v[2 * j + 1][e]);
            float a = v[2 * j][e], b = v[2 * j + 1][e];
            v[2 * j][e] = a + b; v[2 * j + 1][e] = a - b;
        }

    // ---- scale + sign + store ----
    const float M = 0.022097086912079608f;  // 2^-5.5
    const int lanebase = ((lane >> 5) & 1) * 256 + ((lane >> 4) & 1) * 128 + (lane & 15) * 4;
#pragma unroll
    for (int k = 0; k < 8; ++k) {
        const float mk = (k >= 6) ? -M : M;
        const int base = ((k >> 2) & 1) * 1024 + ((k >> 1) & 1) * 512 + (k & 1) * 64;
        f4 t;
        t[0] = v[k][0] * mk; t[1] = v[k][1] * mk;
        t[2] = v[k][2] * mk; t[3] = v[k][3] * mk;
        __builtin_nontemporal_store(t, reinterpret_cast<f4*>(outr + base + lanebase));
    }
}

__global__ __launch_bounds__(256, 4) void fwht_sign_kernel(const float* __restrict__ x,
                                                           float* __restrict__ out,
                                                           int waves_total) {
    const int lane = threadIdx.x & 63;
    const int wid  = threadIdx.x >> 6;
    const int wave = blockIdx.x * 4 + wid;

    f4 cur[8], nxt[8];

    // prologue: load row for r=0
    {
        const float* __restrict__ xr = x + (long long)wave * NN;
#pragma unroll
        for (int k = 0; k < 8; ++k)
            cur[k] = *reinterpret_cast<const f4*>(xr + 256 * k + 4 * lane);
    }

#pragma unroll
    for (int r = 0; r < RPW; ++r) {
        // prefetch row r+1 BEFORE computing row r (overlaps compute+stores)
        if (r + 1 < RPW) {
            const float* __restrict__ xn =
                x + ((long long)wave + (long long)(r + 1) * waves_total) * NN;
#pragma unroll
            for (int k = 0; k < 8; ++k)
                nxt[k] = *reinterpret_cast<const f4*>(xn + 256 * k + 4 * lane);
        }

        float* __restrict__ outr =
            out + ((long long)wave + (long long)r * waves_total) * NN;
        fwht_row_store(cur, outr, lane);

#pragma unroll
        for (int k = 0; k < 8; ++k) cur[k] = nxt[k];
    }
}

extern "C" void kernel_launch(void* const* d_in, const int* in_sizes, int n_in,
                              void* d_out, int out_size, void* d_ws, size_t ws_size,
                              hipStream_t stream) {
    const float* x = (const float*)d_in[0];
    float* out = (float*)d_out;
    const int rows = in_sizes[0] / NN;       // 16384
    const int waves_total = rows / RPW;      // 4096
    const int blocks = waves_total / 4;      // 1024
    fwht_sign_kernel<<<dim3(blocks), dim3(256), 0, stream>>>(x, out, waves_total);
}